// Round 20
// baseline (201.034 us; speedup 1.0000x reference)
//
#include <hip/hip_runtime.h>

#define D 128
#define NBIN 256
#define K1_EPB 4096     // edges per block in hist/scatter (256 thr x 16)
#define BCAP 6144       // per-bin LDS capacity (mean bin size ~3061, sd ~55)

typedef __attribute__((ext_vector_type(8)))  short s16x8;
typedef __attribute__((ext_vector_type(4)))  short s16x4;
typedef __attribute__((ext_vector_type(16))) float f32x16;

static __device__ __forceinline__ unsigned short f2bf(float x) {
    unsigned u = __builtin_bit_cast(unsigned, x);
    unsigned r = (u + 0x7FFF + ((u >> 16) & 1)) >> 16;   // RNE
    return (unsigned short)r;
}
static __device__ __forceinline__ float bf2f(unsigned short h) {
    unsigned u = ((unsigned)h) << 16;
    return __builtin_bit_cast(float, u);
}
static __device__ __forceinline__ float bflo(unsigned v) {
    return __builtin_bit_cast(float, v << 16);
}
static __device__ __forceinline__ float bfhi(unsigned v) {
    return __builtin_bit_cast(float, v & 0xFFFF0000u);
}

// ---------------- pre-kernel: {hist_rank both graphs | st tobf16 | feat tobf16 | prep_weights} ----------------

__global__ __launch_bounds__(256) void pre_kernel(
    const int* __restrict__ dst1, int E1, int nblk1, int* __restrict__ hist1,
    unsigned short* __restrict__ rank1,
    const int* __restrict__ dst2, int E2, int nblk2, int* __restrict__ hist2,
    unsigned short* __restrict__ rank2,
    const float* __restrict__ h_station, unsigned short* __restrict__ st_h,
    int ns_elem, int nbs,
    const float* __restrict__ h_feature, unsigned short* __restrict__ feat_h,
    int nf_elem, int nbf,
    const float* __restrict__ Wself, const float* __restrict__ Wneigh,
    short* __restrict__ wt)
{
    __shared__ int h[NBIN];
    int b = blockIdx.x;
    int t = threadIdx.x;
    if (b < nblk1 + nblk2) {
        const int* dst; int E, nblk; int* hist; unsigned short* rank;
        if (b < nblk1) { dst = dst1; E = E1; nblk = nblk1; hist = hist1; rank = rank1; }
        else { b -= nblk1; dst = dst2; E = E2; nblk = nblk2; hist = hist2; rank = rank2; }
        h[t] = 0;
        __syncthreads();
        int base = b * K1_EPB;
        #pragma unroll 1
        for (int j = 0; j < 16; ++j) {
            int i = base + j * 256 + t;
            if (i < E) {
                int bin = dst[i] >> 8;
                int r = atomicAdd(&h[bin], 1);
                rank[i] = (unsigned short)r;
            }
        }
        __syncthreads();
        hist[t * nblk + b] = h[t];
        return;
    }
    b -= nblk1 + nblk2;
    if (b < nbs) {
        int i = (b * 256 + t) * 4;
        if (i < ns_elem) {
            float4 v = *(const float4*)(h_station + i);
            s16x4 hv;
            hv[0] = (short)f2bf(v.x);
            hv[1] = (short)f2bf(v.y);
            hv[2] = (short)f2bf(v.z);
            hv[3] = (short)f2bf(v.w);
            *(s16x4*)(st_h + i) = hv;
        }
        return;
    }
    b -= nbs;
    if (b < nbf) {
        int i = (b * 256 + t) * 4;
        if (i < nf_elem) {
            float4 v = *(const float4*)(h_feature + i);
            s16x4 hv;
            hv[0] = (short)f2bf(v.x);
            hv[1] = (short)f2bf(v.y);
            hv[2] = (short)f2bf(v.z);
            hv[3] = (short)f2bf(v.w);
            *(s16x4*)(feat_h + i) = hv;
        }
        return;
    }
    b -= nbf;
    {
        int g = b * 256 + t;                 // [0, 16384)
        int m = g >> 11;
        int e = g & 2047;
        int n  = e >> 4;
        int kg = e & 15;
        int kk0 = kg >> 3;
        int kl0 = (kg & 7) * 8;
        int pair = m >> 1, s = m & 1;
        int l = (pair == 3) ? 2 : ((pair == 2) ? 1 : 0);
        int r = (pair == 0) ? 0 : 1;
        const float* W = (s ? Wneigh : Wself) + (size_t)(l * 2 + r) * D * D;
        s16x8 hv;
        #pragma unroll
        for (int c = 0; c < 8; ++c) {
            int k = kk0 * 64 + kl0 + c;
            hv[c] = (short)f2bf(W[(size_t)k * D + n]);
        }
        int ksb = kl0 ^ ((n & 7) << 3);
        size_t base = ((size_t)(pair * 2 + s) * 2 + kk0) * 8192;
        *(s16x8*)&wt[base + n * 64 + ksb] = hv;
    }
}

// ---------------- CSR build: scans, scatter, per-bin counting sort ----------------

__global__ __launch_bounds__(256) void scan_blocks_g(
    const int* __restrict__ in1, int* __restrict__ out1, int* __restrict__ bs1, int L1,
    const int* __restrict__ in2, int* __restrict__ out2, int* __restrict__ bs2, int L2,
    int nb1)
{
    int gid = blockIdx.x;
    const int* in; int* out; int* bs; int b; int L;
    if (gid < nb1) { in = in1; out = out1; bs = bs1; b = gid; L = L1; }
    else          { in = in2; out = out2; bs = bs2; b = gid - nb1; L = L2; }
    int t = threadIdx.x;
    int i0 = b * 1024 + t * 4;
    int4 v = make_int4(0, 0, 0, 0);
    if (i0 + 3 < L) v = *(const int4*)(in + i0);
    else {
        if (i0 + 0 < L) v.x = in[i0 + 0];
        if (i0 + 1 < L) v.y = in[i0 + 1];
        if (i0 + 2 < L) v.z = in[i0 + 2];
        if (i0 + 3 < L) v.w = in[i0 + 3];
    }
    __shared__ int sm[256];
    sm[t] = v.x + v.y + v.z + v.w;
    __syncthreads();
    for (int off = 1; off < 256; off <<= 1) {
        int x = (t >= off) ? sm[t - off] : 0;
        __syncthreads();
        sm[t] += x;
        __syncthreads();
    }
    int excl = (t > 0) ? sm[t - 1] : 0;
    if (i0 + 0 < L) out[i0 + 0] = excl;
    if (i0 + 1 < L) out[i0 + 1] = excl + v.x;
    if (i0 + 2 < L) out[i0 + 2] = excl + v.x + v.y;
    if (i0 + 3 < L) out[i0 + 3] = excl + v.x + v.y + v.z;
    if (t == 255) bs[b] = sm[255];
}

__global__ __launch_bounds__(256) void scan_offsets_g(
    int* __restrict__ out1, const int* __restrict__ bs1, int L1,
    int* __restrict__ out2, const int* __restrict__ bs2, int L2, int nb1)
{
    int gid = blockIdx.x;
    int* out; const int* bs; int b; int L;
    if (gid < nb1) { out = out1; bs = bs1; b = gid; L = L1; }
    else          { out = out2; bs = bs2; b = gid - nb1; L = L2; }
    int t = threadIdx.x;
    int lane = t & 63;
    int partial = 0;
    for (int i = lane; i < b; i += 64) partial += bs[i];
    #pragma unroll
    for (int off = 32; off; off >>= 1) partial += __shfl_xor(partial, off);
    if (partial == 0) return;
    int i0 = b * 1024 + t * 4;
    if (i0 + 0 < L) out[i0 + 0] += partial;
    if (i0 + 1 < L) out[i0 + 1] += partial;
    if (i0 + 2 < L) out[i0 + 2] += partial;
    if (i0 + 3 < L) out[i0 + 3] += partial;
}

__global__ __launch_bounds__(256) void scatter_kernel(
    const int* __restrict__ dst1, const int* __restrict__ src1,
    const unsigned short* __restrict__ rank1, const int* __restrict__ off1,
    unsigned* __restrict__ bkt1, int E1, int nblk1,
    const int* __restrict__ dst2, const int* __restrict__ src2,
    const unsigned short* __restrict__ rank2, const int* __restrict__ off2,
    unsigned* __restrict__ bkt2, int E2, int nblk2)
{
    int b = blockIdx.x;
    const int* dst; const int* src; const unsigned short* rank; const int* off;
    unsigned* bkt; int E, nblk;
    if (b < nblk1) { dst = dst1; src = src1; rank = rank1; off = off1; bkt = bkt1; E = E1; nblk = nblk1; }
    else { b -= nblk1; dst = dst2; src = src2; rank = rank2; off = off2; bkt = bkt2; E = E2; nblk = nblk2; }
    int t = threadIdx.x;
    int base = b * K1_EPB;
    #pragma unroll 1
    for (int j = 0; j < 16; ++j) {
        int i = base + j * 256 + t;
        if (i < E) {
            int d = dst[i];
            int bin = d >> 8;
            int pos = off[bin * nblk + b] + rank[i];
            bkt[pos] = ((unsigned)(d & 255) << 24) | (unsigned)src[i];
        }
    }
}

__global__ __launch_bounds__(256) void bucket_csr_kernel(
    const unsigned* __restrict__ bkt1, const int* __restrict__ off1, int E1, int nblk1,
    int* __restrict__ col1, int* __restrict__ rp1,
    const unsigned* __restrict__ bkt2, const int* __restrict__ off2, int E2, int nblk2,
    int* __restrict__ col2, int* __restrict__ rp2, int NSn)
{
    __shared__ int h[NBIN];
    __shared__ int pre[NBIN];
    __shared__ int cur[NBIN];
    __shared__ int colbuf[BCAP];
    int bin = blockIdx.x;
    const unsigned* bkt; const int* off; int E, nblk; int* col; int* rp;
    if (bin < NBIN) { bkt = bkt1; off = off1; E = E1; nblk = nblk1; col = col1; rp = rp1; }
    else { bin -= NBIN; bkt = bkt2; off = off2; E = E2; nblk = nblk2; col = col2; rp = rp2; }
    int t = threadIdx.x;
    int start = off[bin * nblk];
    int end = (bin == NBIN - 1) ? E : off[(bin + 1) * nblk];
    int n = end - start;

    h[t] = 0;
    __syncthreads();
    for (int p = t; p < n; p += 256) atomicAdd(&h[bkt[start + p] >> 24], 1);
    __syncthreads();
    int hv = h[t];
    pre[t] = hv;
    __syncthreads();
    for (int o = 1; o < 256; o <<= 1) {
        int x = (t >= o) ? pre[t - o] : 0;
        __syncthreads();
        pre[t] += x;
        __syncthreads();
    }
    int excl = pre[t] - hv;
    cur[t] = excl;
    __syncthreads();
    for (int p = t; p < n; p += 256) {
        unsigned v = bkt[start + p];
        int lo = v >> 24;
        int pos = atomicAdd(&cur[lo], 1);
        if (pos < BCAP) colbuf[pos] = (int)(v & 0xFFFFFF);
    }
    __syncthreads();
    for (int p = t; p < n; p += 256) col[start + p] = colbuf[p];
    int dstid = bin * 256 + t;
    if (dstid < NSn) rp[dstid] = start + excl;
    if (bin == 0 && t == 0) rp[NSn] = E;
}

// ---------------- fused layer (512 threads): agg (Gg -> LDS N-tile) + GEMM (self Sg) ----------------
// r20: phase-1 gather deepened to 4 independent loads in flight (was 2) —
// per-wave serial chain was the critical path (deg~12 -> 3 latency batches vs 6).

template<bool ACC, bool WF32>
__global__ __launch_bounds__(512) void fused_layer_kernel(
    const unsigned short* __restrict__ Sg,     // self operand
    const unsigned short* __restrict__ Gg,     // gather source
    const int* __restrict__ rowptr, const int* __restrict__ col,
    const short* __restrict__ wtp, const float* __restrict__ bias,
    float* __restrict__ Yf, unsigned short* __restrict__ Yh, int M)
{
    __shared__ short lds[20480];     // 40KB
    short* NhS = lds;                // [64][128] n tile, swizzled (16KB)
    short* AhS = lds + 8192;         // A stage (8KB)
    short* BhS = lds + 12288;        // B stage (16KB)

    const int tid = threadIdx.x;
    const int l = tid & 63, w = tid >> 6;      // 8 waves
    const int wr = w >> 2, wc = w & 3;
    const int row0 = blockIdx.x * 64;

    // ---- phase 1: 8 rows per wave into NhS (zeros for pad rows), 4-deep ILP ----
    {
        const int q  = l >> 4;
        const int ql = l & 15;
        const unsigned short* base = Gg + ql * 8;
        #pragma unroll 1
        for (int it = 0; it < 2; ++it) {
            int lrow = w * 8 + it * 4 + q;
            int row = row0 + lrow;
            int beg = 0, end = 0;
            if (row < M) { beg = rowptr[row]; end = rowptr[row + 1]; }
            int deg = end - beg;
            float a0 = 0.f, a1 = 0.f, a2 = 0.f, a3 = 0.f;
            float a4 = 0.f, a5 = 0.f, a6 = 0.f, a7 = 0.f;
            for (int b = beg; b < end; b += 16) {
                int n = min(16, end - b);
                int myidx = (ql < n) ? col[b + ql] : 0;
                int j = 0;
                for (; j + 4 <= n; j += 4) {
                    int s0 = __shfl(myidx, (q << 4) + j);
                    int s1 = __shfl(myidx, (q << 4) + j + 1);
                    int s2 = __shfl(myidx, (q << 4) + j + 2);
                    int s3 = __shfl(myidx, (q << 4) + j + 3);
                    uint4 v0 = *(const uint4*)(base + (size_t)s0 * D);
                    uint4 v1 = *(const uint4*)(base + (size_t)s1 * D);
                    uint4 v2 = *(const uint4*)(base + (size_t)s2 * D);
                    uint4 v3 = *(const uint4*)(base + (size_t)s3 * D);
                    a0 += bflo(v0.x); a1 += bfhi(v0.x);
                    a2 += bflo(v0.y); a3 += bfhi(v0.y);
                    a4 += bflo(v0.z); a5 += bfhi(v0.z);
                    a6 += bflo(v0.w); a7 += bfhi(v0.w);
                    a0 += bflo(v1.x); a1 += bfhi(v1.x);
                    a2 += bflo(v1.y); a3 += bfhi(v1.y);
                    a4 += bflo(v1.z); a5 += bfhi(v1.z);
                    a6 += bflo(v1.w); a7 += bfhi(v1.w);
                    a0 += bflo(v2.x); a1 += bfhi(v2.x);
                    a2 += bflo(v2.y); a3 += bfhi(v2.y);
                    a4 += bflo(v2.z); a5 += bfhi(v2.z);
                    a6 += bflo(v2.w); a7 += bfhi(v2.w);
                    a0 += bflo(v3.x); a1 += bfhi(v3.x);
                    a2 += bflo(v3.y); a3 += bfhi(v3.y);
                    a4 += bflo(v3.z); a5 += bfhi(v3.z);
                    a6 += bflo(v3.w); a7 += bfhi(v3.w);
                }
                for (; j + 2 <= n; j += 2) {
                    int s0 = __shfl(myidx, (q << 4) + j);
                    int s1 = __shfl(myidx, (q << 4) + j + 1);
                    uint4 v0 = *(const uint4*)(base + (size_t)s0 * D);
                    uint4 v1 = *(const uint4*)(base + (size_t)s1 * D);
                    a0 += bflo(v0.x); a1 += bfhi(v0.x);
                    a2 += bflo(v0.y); a3 += bfhi(v0.y);
                    a4 += bflo(v0.z); a5 += bfhi(v0.z);
                    a6 += bflo(v0.w); a7 += bfhi(v0.w);
                    a0 += bflo(v1.x); a1 += bfhi(v1.x);
                    a2 += bflo(v1.y); a3 += bfhi(v1.y);
                    a4 += bflo(v1.z); a5 += bfhi(v1.z);
                    a6 += bflo(v1.w); a7 += bfhi(v1.w);
                }
                if (j < n) {
                    int s0 = __shfl(myidx, (q << 4) + j);
                    uint4 v0 = *(const uint4*)(base + (size_t)s0 * D);
                    a0 += bflo(v0.x); a1 += bfhi(v0.x);
                    a2 += bflo(v0.y); a3 += bfhi(v0.y);
                    a4 += bflo(v0.z); a5 += bfhi(v0.z);
                    a6 += bflo(v0.w); a7 += bfhi(v0.w);
                }
            }
            float inv = 1.0f / fmaxf((float)deg, 1.0f);
            s16x8 o;
            o[0] = (short)f2bf(a0 * inv);
            o[1] = (short)f2bf(a1 * inv);
            o[2] = (short)f2bf(a2 * inv);
            o[3] = (short)f2bf(a3 * inv);
            o[4] = (short)f2bf(a4 * inv);
            o[5] = (short)f2bf(a5 * inv);
            o[6] = (short)f2bf(a6 * inv);
            o[7] = (short)f2bf(a7 * inv);
            int sw = (lrow & 7) << 3;
            *(s16x8*)&NhS[lrow * 128 + (ql >> 3) * 64 + (((ql & 7) * 8) ^ sw)] = o;
        }
    }

    // ---- phase 2: GEMM (self via AhS; N from NhS); wave = (wr, wc), 32x32 out ----
    f32x16 acc = {};
    const int s_row = tid >> 3;          // 0..63
    const int s_k   = (tid & 7) * 8;     // 0..56
    const int s_sw  = (s_row & 7) << 3;
    const int arow  = wr * 32 + (l & 31);
    const int fsw   = (l & 7) << 3;
    const int afk   = (l >> 5) * 8;
    const int brow  = wc * 32 + (l & 31);

    #pragma unroll 1
    for (int st = 0; st < 4; ++st) {
        bool selfst = (st < 2);
        s16x8 a0;
        if (selfst)
            a0 = *(const s16x8*)(Sg + (size_t)(row0 + s_row) * D + (st & 1) * 64 + s_k);
        const short* wsrc = wtp + (size_t)st * 8192;
        s16x8 b0 = *(const s16x8*)(wsrc + tid * 8);
        s16x8 b1 = *(const s16x8*)(wsrc + 4096 + tid * 8);
        __syncthreads();          // st=0: also closes phase 1 (NhS writes)
        if (selfst)
            *(s16x8*)&AhS[s_row * 64 + (s_k ^ s_sw)] = a0;
        *(s16x8*)&BhS[tid * 8]        = b0;
        *(s16x8*)&BhS[4096 + tid * 8] = b1;
        __syncthreads();
        #pragma unroll
        for (int kc = 0; kc < 4; ++kc) {
            int ak = (kc * 16 + afk) ^ fsw;
            s16x8 ah = selfst ? *(const s16x8*)&AhS[arow * 64 + ak]
                              : *(const s16x8*)&NhS[arow * 128 + (st & 1) * 64 + ak];
            s16x8 bh = *(const s16x8*)&BhS[brow * 64 + ak];
            acc = __builtin_amdgcn_mfma_f32_32x32x16_bf16(ah, bh, acc, 0, 0, 0);
        }
    }

    // ---- epilogue ----
    __syncthreads();
    float* fstage = (float*)lds;     // 32KB of the 40KB
    const int colb = l & 31;
    const int rq4  = (l >> 5) * 4;
    {
        int col2 = wc * 32 + colb;
        float bias_c = bias[col2];
        #pragma unroll
        for (int g = 0; g < 4; ++g) {
            #pragma unroll
            for (int q = 0; q < 4; ++q) {
                int r = wr * 32 + q + g * 8 + rq4;
                fstage[r * 128 + col2] = fmaxf(acc[g * 4 + q] + bias_c, 0.f);
            }
        }
    }
    __syncthreads();
    int orow = tid >> 3;             // 0..63
    int ocol = (tid & 7) * 16;       // 0..112
    int grow = row0 + orow;
    if (grow < M) {
        size_t base = (size_t)grow * D + ocol;
        float vals[16];
        #pragma unroll
        for (int c = 0; c < 16; c += 4)
            *(float4*)&vals[c] = *(const float4*)&fstage[orow * 128 + ocol + c];
        if (ACC) {
            #pragma unroll
            for (int c8 = 0; c8 < 2; ++c8) {
                s16x8 oh = *(const s16x8*)(Yh + base + c8 * 8);
                #pragma unroll
                for (int e = 0; e < 8; ++e)
                    vals[c8 * 8 + e] += bf2f((unsigned short)oh[e]);
            }
        }
        if (WF32) {
            #pragma unroll
            for (int c = 0; c < 16; c += 4)
                *(float4*)(Yf + base + c) = *(const float4*)&vals[c];
        } else {
            #pragma unroll
            for (int c8 = 0; c8 < 2; ++c8) {
                s16x8 hv;
                #pragma unroll
                for (int e = 0; e < 8; ++e)
                    hv[e] = (short)f2bf(vals[c8 * 8 + e]);
                *(s16x8*)(Yh + base + c8 * 8) = hv;
            }
        }
    }
}

// ---------------- launch ----------------

extern "C" void kernel_launch(void* const* d_in, const int* in_sizes, int n_in,
                              void* d_out, int out_size, void* d_ws, size_t ws_size,
                              hipStream_t stream) {
    const float* h_station = (const float*)d_in[0];
    const float* h_feature = (const float*)d_in[1];
    const float* Wself     = (const float*)d_in[2];
    const float* Wneigh    = (const float*)d_in[3];
    const float* bias      = (const float*)d_in[4];
    const int* hf_src = (const int*)d_in[5];
    const int* hf_dst = (const int*)d_in[6];
    const int* tt_src = (const int*)d_in[7];
    const int* tt_dst = (const int*)d_in[8];

    const int NS = in_sizes[0] / D;
    const int NF = in_sizes[1] / D;
    const int E1 = in_sizes[5];
    const int E2 = in_sizes[7];
    const int NSP = (NS + 63) & ~63;

    char* ws = (char*)d_ws;
    size_t off = 0;
    auto alloc = [&](size_t bytes) -> void* {
        void* p = ws + off;
        off = (off + bytes + 255) & ~(size_t)255;
        return p;
    };
    unsigned short* st_h  = (unsigned short*)alloc((size_t)NSP * D * 2);
    unsigned short* n_h   = (unsigned short*)alloc((size_t)NSP * D * 2);   // feat backing (part 1)
    unsigned short* n_h2  = (unsigned short*)alloc((size_t)NSP * D * 2);   // feat backing (part 2)
    unsigned short* hbreg = (unsigned short*)alloc((size_t)2 * NSP * D * 2);
    unsigned short* hb0   = hbreg;
    unsigned short* hb1   = hbreg + (size_t)NSP * D;
    int* rp_hf    = (int*)alloc((size_t)(NS + 1) * sizeof(int));
    int* col_hf   = (int*)alloc((size_t)E1 * sizeof(int));
    int* rp_tt    = (int*)alloc((size_t)(NS + 1) * sizeof(int));
    int* col_tt   = (int*)alloc((size_t)E2 * sizeof(int));
    short* wt     = (short*)alloc((size_t)4 * 32768 * sizeof(short));

    const int nblk1 = (E1 + K1_EPB - 1) / K1_EPB;
    const int nblk2 = (E2 + K1_EPB - 1) / K1_EPB;
    const int L1 = NBIN * nblk1;
    const int L2 = NBIN * nblk2;
    int* hist1 = (int*)alloc((size_t)L1 * sizeof(int));
    int* hist2 = (int*)alloc((size_t)L2 * sizeof(int));
    int* off1  = (int*)alloc((size_t)L1 * sizeof(int));
    int* off2  = (int*)alloc((size_t)L2 * sizeof(int));
    unsigned short* rank1 = (unsigned short*)alloc((size_t)E1 * 2);
    unsigned short* rank2 = (unsigned short*)alloc((size_t)E2 * 2);
    unsigned* bkt1 = (unsigned*)alloc((size_t)E1 * sizeof(unsigned));
    unsigned* bkt2 = (unsigned*)alloc((size_t)E2 * sizeof(unsigned));
    const int nbs1 = (L1 + 1023) / 1024;
    const int nbs2 = (L2 + 1023) / 1024;
    int* bsA = (int*)alloc((size_t)nbs1 * sizeof(int));
    int* bsB = (int*)alloc((size_t)nbs2 * sizeof(int));

    // feat lives in n_h+n_h2 (contiguous, >= NF*D*2)
    unsigned short* feat_h = n_h;

    const int tpb = 256;
    int nbs = (NS * D / 4 + tpb - 1) / tpb;
    int nbf = (NF * D / 4 + tpb - 1) / tpb;

    // ---- CSR build (atomic-free) + conversions ----
    pre_kernel<<<nblk1 + nblk2 + nbs + nbf + 64, tpb, 0, stream>>>(
        hf_dst, E1, nblk1, hist1, rank1, tt_dst, E2, nblk2, hist2, rank2,
        h_station, st_h, NS * D, nbs, h_feature, feat_h, NF * D, nbf,
        Wself, Wneigh, wt);
    scan_blocks_g<<<nbs1 + nbs2, tpb, 0, stream>>>(
        hist1, off1, bsA, L1, hist2, off2, bsB, L2, nbs1);
    scan_offsets_g<<<nbs1 + nbs2, tpb, 0, stream>>>(
        off1, bsA, L1, off2, bsB, L2, nbs1);
    scatter_kernel<<<nblk1 + nblk2, tpb, 0, stream>>>(
        hf_dst, hf_src, rank1, off1, bkt1, E1, nblk1,
        tt_dst, tt_src, rank2, off2, bkt2, E2, nblk2);
    bucket_csr_kernel<<<2 * NBIN, tpb, 0, stream>>>(
        bkt1, off1, E1, nblk1, col_hf, rp_hf,
        bkt2, off2, E2, nblk2, col_tt, rp_tt, NS);

    int ggemm = NSP / 64;
    auto BI = [&](int lidx, int r) { return bias + (size_t)(lidx * 2 + r) * D; };
    auto WT = [&](int pair) { return wt + (size_t)pair * 32768; };
    float* out = (float*)d_out;

    // ---- layer 1a: self=st, gather=feat (hf-CSR) -> hb0 ----
    fused_layer_kernel<false, false><<<ggemm, 512, 0, stream>>>(
        st_h, feat_h, rp_hf, col_hf, WT(0), BI(0,0), nullptr, hb0, NS);
    // ---- layer 1b: self=st, gather=st (tt-CSR), ACC hb0 -> hb0 ----
    fused_layer_kernel<true, false><<<ggemm, 512, 0, stream>>>(
        st_h, st_h, rp_tt, col_tt, WT(1), BI(0,1), nullptr, hb0, NS);
    // ---- layer 2: self=gather=hb0 -> hb1 ----
    fused_layer_kernel<false, false><<<ggemm, 512, 0, stream>>>(
        hb0, hb0, rp_tt, col_tt, WT(2), BI(1,1), nullptr, hb1, NS);
    // ---- layer 3: self=gather=hb1 -> out (fp32) ----
    fused_layer_kernel<false, true><<<ggemm, 512, 0, stream>>>(
        hb1, hb1, rp_tt, col_tt, WT(3), BI(2,1), out, nullptr, NS);
}

// Round 21
// 183.833 us; speedup vs baseline: 1.0936x; 1.0936x over previous
//
#include <hip/hip_runtime.h>

#define D 128
#define NBIN 256
#define K1_EPB 4096     // edges per block in hist/scatter (256 thr x 16)
#define BCAP 6144       // per-bin LDS capacity (mean bin size ~3061, sd ~55)

typedef __attribute__((ext_vector_type(8)))  short s16x8;
typedef __attribute__((ext_vector_type(4)))  short s16x4;
typedef __attribute__((ext_vector_type(16))) float f32x16;

static __device__ __forceinline__ unsigned short f2bf(float x) {
    unsigned u = __builtin_bit_cast(unsigned, x);
    unsigned r = (u + 0x7FFF + ((u >> 16) & 1)) >> 16;   // RNE
    return (unsigned short)r;
}
static __device__ __forceinline__ float bf2f(unsigned short h) {
    unsigned u = ((unsigned)h) << 16;
    return __builtin_bit_cast(float, u);
}
static __device__ __forceinline__ float bflo(unsigned v) {
    return __builtin_bit_cast(float, v << 16);
}
static __device__ __forceinline__ float bfhi(unsigned v) {
    return __builtin_bit_cast(float, v & 0xFFFF0000u);
}

// ---------------- pre-kernel: {hist_rank both graphs | st tobf16 | feat tobf16 | prep_weights} ----------------

__global__ __launch_bounds__(256) void pre_kernel(
    const int* __restrict__ dst1, int E1, int nblk1, int* __restrict__ hist1,
    unsigned short* __restrict__ rank1,
    const int* __restrict__ dst2, int E2, int nblk2, int* __restrict__ hist2,
    unsigned short* __restrict__ rank2,
    const float* __restrict__ h_station, unsigned short* __restrict__ st_h,
    int ns_elem, int nbs,
    const float* __restrict__ h_feature, unsigned short* __restrict__ feat_h,
    int nf_elem, int nbf,
    const float* __restrict__ Wself, const float* __restrict__ Wneigh,
    short* __restrict__ wt)
{
    __shared__ int h[NBIN];
    int b = blockIdx.x;
    int t = threadIdx.x;
    if (b < nblk1 + nblk2) {
        const int* dst; int E, nblk; int* hist; unsigned short* rank;
        if (b < nblk1) { dst = dst1; E = E1; nblk = nblk1; hist = hist1; rank = rank1; }
        else { b -= nblk1; dst = dst2; E = E2; nblk = nblk2; hist = hist2; rank = rank2; }
        h[t] = 0;
        __syncthreads();
        int base = b * K1_EPB;
        #pragma unroll 1
        for (int j = 0; j < 16; ++j) {
            int i = base + j * 256 + t;
            if (i < E) {
                int bin = dst[i] >> 8;
                int r = atomicAdd(&h[bin], 1);
                rank[i] = (unsigned short)r;
            }
        }
        __syncthreads();
        hist[t * nblk + b] = h[t];
        return;
    }
    b -= nblk1 + nblk2;
    if (b < nbs) {
        int i = (b * 256 + t) * 4;
        if (i < ns_elem) {
            float4 v = *(const float4*)(h_station + i);
            s16x4 hv;
            hv[0] = (short)f2bf(v.x);
            hv[1] = (short)f2bf(v.y);
            hv[2] = (short)f2bf(v.z);
            hv[3] = (short)f2bf(v.w);
            *(s16x4*)(st_h + i) = hv;
        }
        return;
    }
    b -= nbs;
    if (b < nbf) {
        int i = (b * 256 + t) * 4;
        if (i < nf_elem) {
            float4 v = *(const float4*)(h_feature + i);
            s16x4 hv;
            hv[0] = (short)f2bf(v.x);
            hv[1] = (short)f2bf(v.y);
            hv[2] = (short)f2bf(v.z);
            hv[3] = (short)f2bf(v.w);
            *(s16x4*)(feat_h + i) = hv;
        }
        return;
    }
    b -= nbf;
    {
        int g = b * 256 + t;                 // [0, 16384)
        int m = g >> 11;
        int e = g & 2047;
        int n  = e >> 4;
        int kg = e & 15;
        int kk0 = kg >> 3;
        int kl0 = (kg & 7) * 8;
        int pair = m >> 1, s = m & 1;
        int l = (pair == 3) ? 2 : ((pair == 2) ? 1 : 0);
        int r = (pair == 0) ? 0 : 1;
        const float* W = (s ? Wneigh : Wself) + (size_t)(l * 2 + r) * D * D;
        s16x8 hv;
        #pragma unroll
        for (int c = 0; c < 8; ++c) {
            int k = kk0 * 64 + kl0 + c;
            hv[c] = (short)f2bf(W[(size_t)k * D + n]);
        }
        int ksb = kl0 ^ ((n & 7) << 3);
        size_t base = ((size_t)(pair * 2 + s) * 2 + kk0) * 8192;
        *(s16x8*)&wt[base + n * 64 + ksb] = hv;
    }
}

// ---------------- CSR build: scans, scatter, per-bin counting sort ----------------

__global__ __launch_bounds__(256) void scan_blocks_g(
    const int* __restrict__ in1, int* __restrict__ out1, int* __restrict__ bs1, int L1,
    const int* __restrict__ in2, int* __restrict__ out2, int* __restrict__ bs2, int L2,
    int nb1)
{
    int gid = blockIdx.x;
    const int* in; int* out; int* bs; int b; int L;
    if (gid < nb1) { in = in1; out = out1; bs = bs1; b = gid; L = L1; }
    else          { in = in2; out = out2; bs = bs2; b = gid - nb1; L = L2; }
    int t = threadIdx.x;
    int i0 = b * 1024 + t * 4;
    int4 v = make_int4(0, 0, 0, 0);
    if (i0 + 3 < L) v = *(const int4*)(in + i0);
    else {
        if (i0 + 0 < L) v.x = in[i0 + 0];
        if (i0 + 1 < L) v.y = in[i0 + 1];
        if (i0 + 2 < L) v.z = in[i0 + 2];
        if (i0 + 3 < L) v.w = in[i0 + 3];
    }
    __shared__ int sm[256];
    sm[t] = v.x + v.y + v.z + v.w;
    __syncthreads();
    for (int off = 1; off < 256; off <<= 1) {
        int x = (t >= off) ? sm[t - off] : 0;
        __syncthreads();
        sm[t] += x;
        __syncthreads();
    }
    int excl = (t > 0) ? sm[t - 1] : 0;
    if (i0 + 0 < L) out[i0 + 0] = excl;
    if (i0 + 1 < L) out[i0 + 1] = excl + v.x;
    if (i0 + 2 < L) out[i0 + 2] = excl + v.x + v.y;
    if (i0 + 3 < L) out[i0 + 3] = excl + v.x + v.y + v.z;
    if (t == 255) bs[b] = sm[255];
}

__global__ __launch_bounds__(256) void scan_offsets_g(
    int* __restrict__ out1, const int* __restrict__ bs1, int L1,
    int* __restrict__ out2, const int* __restrict__ bs2, int L2, int nb1)
{
    int gid = blockIdx.x;
    int* out; const int* bs; int b; int L;
    if (gid < nb1) { out = out1; bs = bs1; b = gid; L = L1; }
    else          { out = out2; bs = bs2; b = gid - nb1; L = L2; }
    int t = threadIdx.x;
    int lane = t & 63;
    int partial = 0;
    for (int i = lane; i < b; i += 64) partial += bs[i];
    #pragma unroll
    for (int off = 32; off; off >>= 1) partial += __shfl_xor(partial, off);
    if (partial == 0) return;
    int i0 = b * 1024 + t * 4;
    if (i0 + 0 < L) out[i0 + 0] += partial;
    if (i0 + 1 < L) out[i0 + 1] += partial;
    if (i0 + 2 < L) out[i0 + 2] += partial;
    if (i0 + 3 < L) out[i0 + 3] += partial;
}

__global__ __launch_bounds__(256) void scatter_kernel(
    const int* __restrict__ dst1, const int* __restrict__ src1,
    const unsigned short* __restrict__ rank1, const int* __restrict__ off1,
    unsigned* __restrict__ bkt1, int E1, int nblk1,
    const int* __restrict__ dst2, const int* __restrict__ src2,
    const unsigned short* __restrict__ rank2, const int* __restrict__ off2,
    unsigned* __restrict__ bkt2, int E2, int nblk2)
{
    int b = blockIdx.x;
    const int* dst; const int* src; const unsigned short* rank; const int* off;
    unsigned* bkt; int E, nblk;
    if (b < nblk1) { dst = dst1; src = src1; rank = rank1; off = off1; bkt = bkt1; E = E1; nblk = nblk1; }
    else { b -= nblk1; dst = dst2; src = src2; rank = rank2; off = off2; bkt = bkt2; E = E2; nblk = nblk2; }
    int t = threadIdx.x;
    int base = b * K1_EPB;
    #pragma unroll 1
    for (int j = 0; j < 16; ++j) {
        int i = base + j * 256 + t;
        if (i < E) {
            int d = dst[i];
            int bin = d >> 8;
            int pos = off[bin * nblk + b] + rank[i];
            bkt[pos] = ((unsigned)(d & 255) << 24) | (unsigned)src[i];
        }
    }
}

__global__ __launch_bounds__(256) void bucket_csr_kernel(
    const unsigned* __restrict__ bkt1, const int* __restrict__ off1, int E1, int nblk1,
    int* __restrict__ col1, int* __restrict__ rp1,
    const unsigned* __restrict__ bkt2, const int* __restrict__ off2, int E2, int nblk2,
    int* __restrict__ col2, int* __restrict__ rp2, int NSn)
{
    __shared__ int h[NBIN];
    __shared__ int pre[NBIN];
    __shared__ int cur[NBIN];
    __shared__ int colbuf[BCAP];
    int bin = blockIdx.x;
    const unsigned* bkt; const int* off; int E, nblk; int* col; int* rp;
    if (bin < NBIN) { bkt = bkt1; off = off1; E = E1; nblk = nblk1; col = col1; rp = rp1; }
    else { bin -= NBIN; bkt = bkt2; off = off2; E = E2; nblk = nblk2; col = col2; rp = rp2; }
    int t = threadIdx.x;
    int start = off[bin * nblk];
    int end = (bin == NBIN - 1) ? E : off[(bin + 1) * nblk];
    int n = end - start;

    h[t] = 0;
    __syncthreads();
    for (int p = t; p < n; p += 256) atomicAdd(&h[bkt[start + p] >> 24], 1);
    __syncthreads();
    int hv = h[t];
    pre[t] = hv;
    __syncthreads();
    for (int o = 1; o < 256; o <<= 1) {
        int x = (t >= o) ? pre[t - o] : 0;
        __syncthreads();
        pre[t] += x;
        __syncthreads();
    }
    int excl = pre[t] - hv;
    cur[t] = excl;
    __syncthreads();
    for (int p = t; p < n; p += 256) {
        unsigned v = bkt[start + p];
        int lo = v >> 24;
        int pos = atomicAdd(&cur[lo], 1);
        if (pos < BCAP) colbuf[pos] = (int)(v & 0xFFFFFF);
    }
    __syncthreads();
    for (int p = t; p < n; p += 256) col[start + p] = colbuf[p];
    int dstid = bin * 256 + t;
    if (dstid < NSn) rp[dstid] = start + excl;
    if (bin == 0 && t == 0) rp[NSn] = E;
}

// ---------------- fused layer (512 threads): agg (Gg -> LDS N-tile) + GEMM (self Sg) ----------------
// r21: reverted to the r19 2-deep gather (r20's 4-deep ILP regressed 184->201us;
// TLP at 32 waves/CU is the right latency-hiding mechanism, not deeper unroll).

template<bool ACC, bool WF32>
__global__ __launch_bounds__(512) void fused_layer_kernel(
    const unsigned short* __restrict__ Sg,     // self operand
    const unsigned short* __restrict__ Gg,     // gather source
    const int* __restrict__ rowptr, const int* __restrict__ col,
    const short* __restrict__ wtp, const float* __restrict__ bias,
    float* __restrict__ Yf, unsigned short* __restrict__ Yh, int M)
{
    __shared__ short lds[20480];     // 40KB
    short* NhS = lds;                // [64][128] n tile, swizzled (16KB)
    short* AhS = lds + 8192;         // A stage (8KB)
    short* BhS = lds + 12288;        // B stage (16KB)

    const int tid = threadIdx.x;
    const int l = tid & 63, w = tid >> 6;      // 8 waves
    const int wr = w >> 2, wc = w & 3;
    const int row0 = blockIdx.x * 64;

    // ---- phase 1: 8 rows per wave into NhS (zeros for pad rows) ----
    {
        const int q  = l >> 4;
        const int ql = l & 15;
        const unsigned short* base = Gg + ql * 8;
        #pragma unroll 1
        for (int it = 0; it < 2; ++it) {
            int lrow = w * 8 + it * 4 + q;
            int row = row0 + lrow;
            int beg = 0, end = 0;
            if (row < M) { beg = rowptr[row]; end = rowptr[row + 1]; }
            int deg = end - beg;
            float a0 = 0.f, a1 = 0.f, a2 = 0.f, a3 = 0.f;
            float a4 = 0.f, a5 = 0.f, a6 = 0.f, a7 = 0.f;
            for (int b = beg; b < end; b += 16) {
                int n = min(16, end - b);
                int myidx = (ql < n) ? col[b + ql] : 0;
                int j = 0;
                for (; j + 2 <= n; j += 2) {
                    int s0 = __shfl(myidx, (q << 4) + j);
                    int s1 = __shfl(myidx, (q << 4) + j + 1);
                    uint4 v0 = *(const uint4*)(base + (size_t)s0 * D);
                    uint4 v1 = *(const uint4*)(base + (size_t)s1 * D);
                    a0 += bflo(v0.x); a1 += bfhi(v0.x);
                    a2 += bflo(v0.y); a3 += bfhi(v0.y);
                    a4 += bflo(v0.z); a5 += bfhi(v0.z);
                    a6 += bflo(v0.w); a7 += bfhi(v0.w);
                    a0 += bflo(v1.x); a1 += bfhi(v1.x);
                    a2 += bflo(v1.y); a3 += bfhi(v1.y);
                    a4 += bflo(v1.z); a5 += bfhi(v1.z);
                    a6 += bflo(v1.w); a7 += bfhi(v1.w);
                }
                if (j < n) {
                    int s0 = __shfl(myidx, (q << 4) + j);
                    uint4 v0 = *(const uint4*)(base + (size_t)s0 * D);
                    a0 += bflo(v0.x); a1 += bfhi(v0.x);
                    a2 += bflo(v0.y); a3 += bfhi(v0.y);
                    a4 += bflo(v0.z); a5 += bfhi(v0.z);
                    a6 += bflo(v0.w); a7 += bfhi(v0.w);
                }
            }
            float inv = 1.0f / fmaxf((float)deg, 1.0f);
            s16x8 o;
            o[0] = (short)f2bf(a0 * inv);
            o[1] = (short)f2bf(a1 * inv);
            o[2] = (short)f2bf(a2 * inv);
            o[3] = (short)f2bf(a3 * inv);
            o[4] = (short)f2bf(a4 * inv);
            o[5] = (short)f2bf(a5 * inv);
            o[6] = (short)f2bf(a6 * inv);
            o[7] = (short)f2bf(a7 * inv);
            int sw = (lrow & 7) << 3;
            *(s16x8*)&NhS[lrow * 128 + (ql >> 3) * 64 + (((ql & 7) * 8) ^ sw)] = o;
        }
    }

    // ---- phase 2: GEMM (self via AhS; N from NhS); wave = (wr, wc), 32x32 out ----
    f32x16 acc = {};
    const int s_row = tid >> 3;          // 0..63
    const int s_k   = (tid & 7) * 8;     // 0..56
    const int s_sw  = (s_row & 7) << 3;
    const int arow  = wr * 32 + (l & 31);
    const int fsw   = (l & 7) << 3;
    const int afk   = (l >> 5) * 8;
    const int brow  = wc * 32 + (l & 31);

    #pragma unroll 1
    for (int st = 0; st < 4; ++st) {
        bool selfst = (st < 2);
        s16x8 a0;
        if (selfst)
            a0 = *(const s16x8*)(Sg + (size_t)(row0 + s_row) * D + (st & 1) * 64 + s_k);
        const short* wsrc = wtp + (size_t)st * 8192;
        s16x8 b0 = *(const s16x8*)(wsrc + tid * 8);
        s16x8 b1 = *(const s16x8*)(wsrc + 4096 + tid * 8);
        __syncthreads();          // st=0: also closes phase 1 (NhS writes)
        if (selfst)
            *(s16x8*)&AhS[s_row * 64 + (s_k ^ s_sw)] = a0;
        *(s16x8*)&BhS[tid * 8]        = b0;
        *(s16x8*)&BhS[4096 + tid * 8] = b1;
        __syncthreads();
        #pragma unroll
        for (int kc = 0; kc < 4; ++kc) {
            int ak = (kc * 16 + afk) ^ fsw;
            s16x8 ah = selfst ? *(const s16x8*)&AhS[arow * 64 + ak]
                              : *(const s16x8*)&NhS[arow * 128 + (st & 1) * 64 + ak];
            s16x8 bh = *(const s16x8*)&BhS[brow * 64 + ak];
            acc = __builtin_amdgcn_mfma_f32_32x32x16_bf16(ah, bh, acc, 0, 0, 0);
        }
    }

    // ---- epilogue ----
    __syncthreads();
    float* fstage = (float*)lds;     // 32KB of the 40KB
    const int colb = l & 31;
    const int rq4  = (l >> 5) * 4;
    {
        int col2 = wc * 32 + colb;
        float bias_c = bias[col2];
        #pragma unroll
        for (int g = 0; g < 4; ++g) {
            #pragma unroll
            for (int q = 0; q < 4; ++q) {
                int r = wr * 32 + q + g * 8 + rq4;
                fstage[r * 128 + col2] = fmaxf(acc[g * 4 + q] + bias_c, 0.f);
            }
        }
    }
    __syncthreads();
    int orow = tid >> 3;             // 0..63
    int ocol = (tid & 7) * 16;       // 0..112
    int grow = row0 + orow;
    if (grow < M) {
        size_t base = (size_t)grow * D + ocol;
        float vals[16];
        #pragma unroll
        for (int c = 0; c < 16; c += 4)
            *(float4*)&vals[c] = *(const float4*)&fstage[orow * 128 + ocol + c];
        if (ACC) {
            #pragma unroll
            for (int c8 = 0; c8 < 2; ++c8) {
                s16x8 oh = *(const s16x8*)(Yh + base + c8 * 8);
                #pragma unroll
                for (int e = 0; e < 8; ++e)
                    vals[c8 * 8 + e] += bf2f((unsigned short)oh[e]);
            }
        }
        if (WF32) {
            #pragma unroll
            for (int c = 0; c < 16; c += 4)
                *(float4*)(Yf + base + c) = *(const float4*)&vals[c];
        } else {
            #pragma unroll
            for (int c8 = 0; c8 < 2; ++c8) {
                s16x8 hv;
                #pragma unroll
                for (int e = 0; e < 8; ++e)
                    hv[e] = (short)f2bf(vals[c8 * 8 + e]);
                *(s16x8*)(Yh + base + c8 * 8) = hv;
            }
        }
    }
}

// ---------------- launch ----------------

extern "C" void kernel_launch(void* const* d_in, const int* in_sizes, int n_in,
                              void* d_out, int out_size, void* d_ws, size_t ws_size,
                              hipStream_t stream) {
    const float* h_station = (const float*)d_in[0];
    const float* h_feature = (const float*)d_in[1];
    const float* Wself     = (const float*)d_in[2];
    const float* Wneigh    = (const float*)d_in[3];
    const float* bias      = (const float*)d_in[4];
    const int* hf_src = (const int*)d_in[5];
    const int* hf_dst = (const int*)d_in[6];
    const int* tt_src = (const int*)d_in[7];
    const int* tt_dst = (const int*)d_in[8];

    const int NS = in_sizes[0] / D;
    const int NF = in_sizes[1] / D;
    const int E1 = in_sizes[5];
    const int E2 = in_sizes[7];
    const int NSP = (NS + 63) & ~63;

    char* ws = (char*)d_ws;
    size_t off = 0;
    auto alloc = [&](size_t bytes) -> void* {
        void* p = ws + off;
        off = (off + bytes + 255) & ~(size_t)255;
        return p;
    };
    unsigned short* st_h  = (unsigned short*)alloc((size_t)NSP * D * 2);
    unsigned short* n_h   = (unsigned short*)alloc((size_t)NSP * D * 2);   // feat backing (part 1)
    unsigned short* n_h2  = (unsigned short*)alloc((size_t)NSP * D * 2);   // feat backing (part 2)
    unsigned short* hbreg = (unsigned short*)alloc((size_t)2 * NSP * D * 2);
    unsigned short* hb0   = hbreg;
    unsigned short* hb1   = hbreg + (size_t)NSP * D;
    int* rp_hf    = (int*)alloc((size_t)(NS + 1) * sizeof(int));
    int* col_hf   = (int*)alloc((size_t)E1 * sizeof(int));
    int* rp_tt    = (int*)alloc((size_t)(NS + 1) * sizeof(int));
    int* col_tt   = (int*)alloc((size_t)E2 * sizeof(int));
    short* wt     = (short*)alloc((size_t)4 * 32768 * sizeof(short));

    const int nblk1 = (E1 + K1_EPB - 1) / K1_EPB;
    const int nblk2 = (E2 + K1_EPB - 1) / K1_EPB;
    const int L1 = NBIN * nblk1;
    const int L2 = NBIN * nblk2;
    int* hist1 = (int*)alloc((size_t)L1 * sizeof(int));
    int* hist2 = (int*)alloc((size_t)L2 * sizeof(int));
    int* off1  = (int*)alloc((size_t)L1 * sizeof(int));
    int* off2  = (int*)alloc((size_t)L2 * sizeof(int));
    unsigned short* rank1 = (unsigned short*)alloc((size_t)E1 * 2);
    unsigned short* rank2 = (unsigned short*)alloc((size_t)E2 * 2);
    unsigned* bkt1 = (unsigned*)alloc((size_t)E1 * sizeof(unsigned));
    unsigned* bkt2 = (unsigned*)alloc((size_t)E2 * sizeof(unsigned));
    const int nbs1 = (L1 + 1023) / 1024;
    const int nbs2 = (L2 + 1023) / 1024;
    int* bsA = (int*)alloc((size_t)nbs1 * sizeof(int));
    int* bsB = (int*)alloc((size_t)nbs2 * sizeof(int));

    // feat lives in n_h+n_h2 (contiguous, >= NF*D*2)
    unsigned short* feat_h = n_h;

    const int tpb = 256;
    int nbs = (NS * D / 4 + tpb - 1) / tpb;
    int nbf = (NF * D / 4 + tpb - 1) / tpb;

    // ---- CSR build (atomic-free) + conversions ----
    pre_kernel<<<nblk1 + nblk2 + nbs + nbf + 64, tpb, 0, stream>>>(
        hf_dst, E1, nblk1, hist1, rank1, tt_dst, E2, nblk2, hist2, rank2,
        h_station, st_h, NS * D, nbs, h_feature, feat_h, NF * D, nbf,
        Wself, Wneigh, wt);
    scan_blocks_g<<<nbs1 + nbs2, tpb, 0, stream>>>(
        hist1, off1, bsA, L1, hist2, off2, bsB, L2, nbs1);
    scan_offsets_g<<<nbs1 + nbs2, tpb, 0, stream>>>(
        off1, bsA, L1, off2, bsB, L2, nbs1);
    scatter_kernel<<<nblk1 + nblk2, tpb, 0, stream>>>(
        hf_dst, hf_src, rank1, off1, bkt1, E1, nblk1,
        tt_dst, tt_src, rank2, off2, bkt2, E2, nblk2);
    bucket_csr_kernel<<<2 * NBIN, tpb, 0, stream>>>(
        bkt1, off1, E1, nblk1, col_hf, rp_hf,
        bkt2, off2, E2, nblk2, col_tt, rp_tt, NS);

    int ggemm = NSP / 64;
    auto BI = [&](int lidx, int r) { return bias + (size_t)(lidx * 2 + r) * D; };
    auto WT = [&](int pair) { return wt + (size_t)pair * 32768; };
    float* out = (float*)d_out;

    // ---- layer 1a: self=st, gather=feat (hf-CSR) -> hb0 ----
    fused_layer_kernel<false, false><<<ggemm, 512, 0, stream>>>(
        st_h, feat_h, rp_hf, col_hf, WT(0), BI(0,0), nullptr, hb0, NS);
    // ---- layer 1b: self=st, gather=st (tt-CSR), ACC hb0 -> hb0 ----
    fused_layer_kernel<true, false><<<ggemm, 512, 0, stream>>>(
        st_h, st_h, rp_tt, col_tt, WT(1), BI(0,1), nullptr, hb0, NS);
    // ---- layer 2: self=gather=hb0 -> hb1 ----
    fused_layer_kernel<false, false><<<ggemm, 512, 0, stream>>>(
        hb0, hb0, rp_tt, col_tt, WT(2), BI(1,1), nullptr, hb1, NS);
    // ---- layer 3: self=gather=hb1 -> out (fp32) ----
    fused_layer_kernel<false, true><<<ggemm, 512, 0, stream>>>(
        hb1, hb1, rp_tt, col_tt, WT(3), BI(2,1), out, nullptr, NS);
}